// Round 4
// baseline (1020.486 us; speedup 1.0000x reference)
//
#include <hip/hip_runtime.h>
#include <stdint.h>

#define B_ 32
#define S_ 512
#define I_ 256
#define H_ 512
#define OUTW 1024
#define OUTS_ELEMS (B_*S_*OUTW)   // 16777216

typedef _Float16 f16;
typedef _Float16 half2_t __attribute__((ext_vector_type(2)));

__device__ __forceinline__ float fdot2(uint32_t a, uint32_t b, float c){
#if __has_builtin(__builtin_amdgcn_fdot2)
  return __builtin_amdgcn_fdot2(__builtin_bit_cast(half2_t, a),
                                __builtin_bit_cast(half2_t, b), c, false);
#else
  half2_t ha = __builtin_bit_cast(half2_t, a);
  half2_t hb = __builtin_bit_cast(half2_t, b);
  return c + (float)ha.x*(float)hb.x + (float)ha.y*(float)hb.y;
#endif
}

__device__ __forceinline__ uint32_t packf16(float x, float y){
  union { f16 h[2]; uint32_t u; } z;
  z.h[0] = (f16)x; z.h[1] = (f16)y;
  return z.u;
}

template<int CTRL>
__device__ __forceinline__ float dpp_xor_add(float x){
  int v = __builtin_amdgcn_update_dpp(0, __float_as_int(x), CTRL, 0xF, 0xF, true);
  return x + __int_as_float(v);
}

// full 8-lane (ks) reduce of 4 accs; returns total for row jg + 64*(ks&3)
__device__ __forceinline__ float reduce8(float a0, float a1, float a2, float a3, int k3){
  a0 = dpp_xor_add<0xB1>(a0); a1 = dpp_xor_add<0xB1>(a1);
  a2 = dpp_xor_add<0xB1>(a2); a3 = dpp_xor_add<0xB1>(a3);
  a0 = dpp_xor_add<0x4E>(a0); a1 = dpp_xor_add<0x4E>(a1);
  a2 = dpp_xor_add<0x4E>(a2); a3 = dpp_xor_add<0x4E>(a3);
  float own = (k3==0)?a0:(k3==1)?a1:(k3==2)?a2:a3;
  return own + __shfl_xor(own, 4);
}

// ---------------------------------------------------------------------------
// P0: W_hh fp32 -> f16 into d_ws
// ---------------------------------------------------------------------------
__global__ __launch_bounds__(256) void cvt_w_kernel(const float* __restrict__ wf,
                                                    const float* __restrict__ wb,
                                                    f16* __restrict__ out){
  int i = blockIdx.x*256 + threadIdx.x;
  const float* src = (i < 32768) ? wf : wb;
  int base = (i & 32767) * 8;
  float4 a = *(const float4*)(src + base);
  float4 c = *(const float4*)(src + base + 4);
  uint4 o;
  o.x = packf16(a.x, a.y); o.y = packf16(a.z, a.w);
  o.z = packf16(c.x, c.y); o.w = packf16(c.z, c.w);
  *(uint4*)(out + (size_t)i*8) = o;
}

// ---------------------------------------------------------------------------
// P1: xp staged into d_out (read once by rnn, then overwritten with h).
// ---------------------------------------------------------------------------
#define PTM 128
#define PTN 64
#define PTK 32
__global__ __launch_bounds__(256) void proj_kernel(
    const float* __restrict__ x,
    const float* __restrict__ wihf, const float* __restrict__ wihb,
    const float* __restrict__ bihf, const float* __restrict__ bhhf,
    const float* __restrict__ bihb, const float* __restrict__ bhhb,
    float* __restrict__ out)
{
  __shared__ float As[PTK][132];
  __shared__ float Bs[PTK][68];
  const int tid = threadIdx.x;
  const int row0 = blockIdx.x * PTM;
  const int j0   = blockIdx.y * PTN;
  const int dir  = (j0 >= 512) ? 1 : 0;
  const int jl0  = j0 - dir*512;
  const float* wih = dir ? wihb : wihf;
  const float* bi  = dir ? bihb : bihf;
  const float* bh  = dir ? bhhb : bhhf;

  const int ty = tid >> 4, tx = tid & 15;
  float acc[8][4];
#pragma unroll
  for (int i=0;i<8;i++)
#pragma unroll
    for (int j=0;j<4;j++) acc[i][j] = 0.f;

  float bias[4];
#pragma unroll
  for (int jj=0;jj<4;jj++){ int jl = jl0 + tx*4 + jj; bias[jj] = bi[jl] + bh[jl]; }

  for (int k0 = 0; k0 < I_; k0 += PTK){
    {
      int r = tid >> 1, kh = (tid & 1) * 16;
      int rg = row0 + r; int bb = rg & 31, tt = rg >> 5;
      const float* ap = x + ((size_t)bb*S_ + tt)*I_ + k0 + kh;
#pragma unroll
      for (int u=0;u<4;u++){
        float4 v = *(const float4*)(ap + u*4);
        As[kh+u*4+0][r] = v.x; As[kh+u*4+1][r] = v.y;
        As[kh+u*4+2][r] = v.z; As[kh+u*4+3][r] = v.w;
      }
    }
    {
      int jr = tid >> 2, kh = (tid & 3) * 8;
      const float* bp = wih + (size_t)(jl0 + jr)*I_ + k0 + kh;
#pragma unroll
      for (int u=0;u<2;u++){
        float4 v = *(const float4*)(bp + u*4);
        Bs[kh+u*4+0][jr] = v.x; Bs[kh+u*4+1][jr] = v.y;
        Bs[kh+u*4+2][jr] = v.z; Bs[kh+u*4+3][jr] = v.w;
      }
    }
    __syncthreads();
#pragma unroll 8
    for (int kk=0; kk<PTK; ++kk){
      const float4 a0 = *(const float4*)&As[kk][ty*8+0];
      const float4 a1 = *(const float4*)&As[kk][ty*8+4];
      const float4 bq = *(const float4*)&Bs[kk][tx*4];
      const float av[8] = {a0.x,a0.y,a0.z,a0.w,a1.x,a1.y,a1.z,a1.w};
      const float bv[4] = {bq.x,bq.y,bq.z,bq.w};
#pragma unroll
      for (int i=0;i<8;i++)
#pragma unroll
        for (int j=0;j<4;j++) acc[i][j] = fmaf(av[i], bv[j], acc[i][j]);
    }
    __syncthreads();
  }
#pragma unroll
  for (int i=0;i<8;i++){
    int rg = row0 + ty*8 + i; int bb = rg & 31, tt = rg >> 5;
    float* op = out + ((size_t)bb*S_ + tt)*OUTW + j0 + tx*4;
    float4 v = {acc[i][0]+bias[0], acc[i][1]+bias[1], acc[i][2]+bias[2], acc[i][3]+bias[3]};
    *(float4*)op = v;
  }
}

// ---------------------------------------------------------------------------
// R: partial-exchange recurrence, weights in 128 NAMED scalar VGPRs.
// 128 WGs; pair = blocks (p, p+64) -> same XCD. WG owns rows [half*256,+256)
// and k-columns [half*256,+256). Per step: phase A = partials for PARTNER's
// rows (publish tagged f16 ASAP), phase B = own rows; owner lane spins on one
// partner dword, relu, store. One barrier/step. 4 ds_read_b128/lane/step.
// ---------------------------------------------------------------------------
#define MAIL_OFF_U32 (1u<<18)        // W f16 = 1 MB = 2^18 u32
#define MAIL_BYTES   (64*2*2*256*4)  // 256 KB

#define DECL16(P) uint32_t P##_0,P##_1,P##_2,P##_3,P##_4,P##_5,P##_6,P##_7, \
                           P##_8,P##_9,P##_10,P##_11,P##_12,P##_13,P##_14,P##_15
#define LOAD16(P, src) do{ const uint4* _q=(const uint4*)(src); \
  uint4 _v0=_q[0],_v1=_q[1],_v2=_q[2],_v3=_q[3]; \
  P##_0=_v0.x; P##_1=_v0.y; P##_2=_v0.z; P##_3=_v0.w; \
  P##_4=_v1.x; P##_5=_v1.y; P##_6=_v1.z; P##_7=_v1.w; \
  P##_8=_v2.x; P##_9=_v2.y; P##_10=_v2.z; P##_11=_v2.w; \
  P##_12=_v3.x;P##_13=_v3.y;P##_14=_v3.z;P##_15=_v3.w; }while(0)
#define KEEP16(P) asm volatile("" : \
  "+v"(P##_0),"+v"(P##_1),"+v"(P##_2),"+v"(P##_3), \
  "+v"(P##_4),"+v"(P##_5),"+v"(P##_6),"+v"(P##_7), \
  "+v"(P##_8),"+v"(P##_9),"+v"(P##_10),"+v"(P##_11), \
  "+v"(P##_12),"+v"(P##_13),"+v"(P##_14),"+v"(P##_15))
#define DOT16(ACC, P) \
  ACC=fdot2(P##_0 ,hv0.x,ACC); ACC=fdot2(P##_1 ,hv0.y,ACC); \
  ACC=fdot2(P##_2 ,hv0.z,ACC); ACC=fdot2(P##_3 ,hv0.w,ACC); \
  ACC=fdot2(P##_4 ,hv1.x,ACC); ACC=fdot2(P##_5 ,hv1.y,ACC); \
  ACC=fdot2(P##_6 ,hv1.z,ACC); ACC=fdot2(P##_7 ,hv1.w,ACC); \
  ACC=fdot2(P##_8 ,hv2.x,ACC); ACC=fdot2(P##_9 ,hv2.y,ACC); \
  ACC=fdot2(P##_10,hv2.z,ACC); ACC=fdot2(P##_11,hv2.w,ACC); \
  ACC=fdot2(P##_12,hv3.x,ACC); ACC=fdot2(P##_13,hv3.y,ACC); \
  ACC=fdot2(P##_14,hv3.z,ACC); ACC=fdot2(P##_15,hv3.w,ACC);

__global__ __launch_bounds__(512, 2) void rnn_kernel(
    const f16* __restrict__ Wall,   // [2][512][512] f16
    const float* __restrict__ h0,   // [2][32][512]
    float* dout, uint32_t* mailbase)
{
  __shared__ char lds[1024];        // 2 parity x 256 f16 (own-half h, swizzled)
  const int tid   = threadIdx.x;
  const int half  = blockIdx.x >> 6;
  const int pairid= blockIdx.x & 63;
  const int dir   = pairid >> 5;
  const int b     = pairid & 31;
  const int jg    = tid >> 3;
  const int ks    = tid & 7;
  const int k3    = ks & 7 & 3;
  const bool owner= (ks < 4);
  const int jl    = jg + 64*k3;     // row (within 256-block) this lane finalizes

  const f16* Wd = Wall + (size_t)dir * (H_*(size_t)H_);
  float* outs = dout + (size_t)b * (S_*OUTW);
  const int col = dir*512 + half*256 + jl;
  float* hn = dout + (size_t)OUTS_ELEMS + ((size_t)dir*B_ + b) * H_;

  uint32_t* mw = mailbase + ((size_t)pairid*2 + half) * 512;       // we write partner rows
  uint32_t* mr = mailbase + ((size_t)pairid*2 + (half^1)) * 512;   // partner writes ours

  // ---- weights into 128 NAMED scalars (8 groups of 16): A* = partner's rows,
  //      B* = own rows; k-slice = own half, ks*32 + [0,32)
  DECL16(A0); DECL16(A1); DECL16(A2); DECL16(A3);
  DECL16(B0); DECL16(B1); DECL16(B2); DECL16(B3);
  {
    const f16* kbase = Wd + half*256 + ks*32;
    LOAD16(A0, kbase + (size_t)((half^1)*256 + jg +   0)*H_);
    LOAD16(A1, kbase + (size_t)((half^1)*256 + jg +  64)*H_);
    LOAD16(A2, kbase + (size_t)((half^1)*256 + jg + 128)*H_);
    LOAD16(A3, kbase + (size_t)((half^1)*256 + jg + 192)*H_);
    LOAD16(B0, kbase + (size_t)( half*256    + jg +   0)*H_);
    LOAD16(B1, kbase + (size_t)( half*256    + jg +  64)*H_);
    LOAD16(B2, kbase + (size_t)( half*256    + jg + 128)*H_);
    LOAD16(B3, kbase + (size_t)( half*256    + jg + 192)*H_);
  }
  // one-time opacity barrier: values become asm results -> cannot be
  // rematerialized from memory; allocator must keep them VGPR-resident.
  KEEP16(A0); KEEP16(A1); KEEP16(A2); KEEP16(A3);
  KEEP16(B0); KEEP16(B1); KEEP16(B2); KEEP16(B3);

  // h LDS layout: logical 16B chunk c (0..31) at physical chunk (c&3)*8+(c>>2)
  const int hwoff = (((jl>>3)&3)*8 + (jl>>5))*16 + (jl&7)*2;   // owner h write
  if (tid < 256){
    int off = (((tid>>3)&3)*8 + (tid>>5))*16 + (tid&7)*2;
    *(f16*)(lds + off) = (f16)h0[((size_t)dir*B_ + b)*H_ + half*256 + tid];
  }
  __syncthreads();

  for (int s=0; s<S_; ++s){
    const int P = s & 1;
    const int t = dir ? (S_-1-s) : s;
    const char* hb = lds + P*512;
    float* xo = outs + (size_t)t*OUTW;
    float xpv = 0.f;
    if (owner) xpv = xo[col];                       // long-latency, hidden by phases

    const uint4 hv0 = *(const uint4*)(hb +       ks*16);
    const uint4 hv1 = *(const uint4*)(hb + 128 + ks*16);
    const uint4 hv2 = *(const uint4*)(hb + 256 + ks*16);
    const uint4 hv3 = *(const uint4*)(hb + 384 + ks*16);

    // ---- phase A: partials for PARTNER's rows; publish ASAP
    {
      float a0=0.f, a1=0.f, a2=0.f, a3=0.f;
      DOT16(a0, A0) DOT16(a1, A1) DOT16(a2, A2) DOT16(a3, A3)
      float totA = reduce8(a0,a1,a2,a3,k3);
      if (owner){
        uint16_t pb = __builtin_bit_cast(uint16_t, (f16)totA);
        uint32_t val = ((uint32_t)pb << 16) | (uint32_t)(s+1);
        __hip_atomic_store(&mw[P*256 + jl], val, __ATOMIC_RELAXED, __HIP_MEMORY_SCOPE_AGENT);
      }
    }
    // ---- phase B: partials for OWN rows (hides partner flight time)
    float totB;
    {
      float b0=0.f, b1=0.f, b2=0.f, b3=0.f;
      DOT16(b0, B0) DOT16(b1, B1) DOT16(b2, B2) DOT16(b3, B3)
      totB = reduce8(b0,b1,b2,b3,k3);
    }
    // ---- finalize: spin on our single partner dword, relu, store
    if (owner){
      const uint32_t tag = (uint32_t)(s+1);
      uint32_t v;
      do {
        v = __hip_atomic_load(&mr[P*256 + jl], __ATOMIC_RELAXED, __HIP_MEMORY_SCOPE_AGENT);
      } while ((v & 0xffffu) != tag);
      float rem = (float)__builtin_bit_cast(f16, (uint16_t)(v >> 16));
      float h = fmaxf(xpv + totB + rem, 0.f);
      xo[col] = h;                                   // overwrite xp slot
      if (s == S_-1) hn[half*256 + jl] = h;
      *(f16*)(lds + (P^1)*512 + hwoff) = (f16)h;
    }
    asm volatile("s_waitcnt lgkmcnt(0)" ::: "memory");
    __builtin_amdgcn_s_barrier();
  }
}

// ---------------------------------------------------------------------------
extern "C" void kernel_launch(void* const* d_in, const int* in_sizes, int n_in,
                              void* d_out, int out_size, void* d_ws, size_t ws_size,
                              hipStream_t stream){
  const float* x    = (const float*)d_in[0];
  const float* h0   = (const float*)d_in[1];
  const float* wihf = (const float*)d_in[2];
  const float* whhf = (const float*)d_in[3];
  const float* bihf = (const float*)d_in[4];
  const float* bhhf = (const float*)d_in[5];
  const float* wihb = (const float*)d_in[6];
  const float* whhb = (const float*)d_in[7];
  const float* bihb = (const float*)d_in[8];
  const float* bhhb = (const float*)d_in[9];
  float* out = (float*)d_out;
  f16* wf16 = (f16*)d_ws;                            // 1 MB
  uint32_t* mail = (uint32_t*)d_ws + MAIL_OFF_U32;   // 256 KB

  hipMemsetAsync((void*)mail, 0, MAIL_BYTES, stream);  // kill stale tags across replays
  cvt_w_kernel<<<256, 256, 0, stream>>>(whhf, whhb, wf16);
  proj_kernel<<<dim3(128, 16), 256, 0, stream>>>(x, wihf, wihb, bihf, bhhf, bihb, bhhb, out);
  rnn_kernel<<<128, 512, 0, stream>>>(wf16, h0, out, mail);
}

// Round 5
// 997.630 us; speedup vs baseline: 1.0229x; 1.0229x over previous
//
#include <hip/hip_runtime.h>
#include <stdint.h>

#define B_ 32
#define S_ 512
#define I_ 256
#define H_ 512
#define OUTW 1024
#define OUTS_ELEMS (B_*S_*OUTW)   // 16777216

typedef _Float16 f16;
typedef _Float16 half2_t __attribute__((ext_vector_type(2)));

__device__ __forceinline__ float fdot2(uint32_t a, uint32_t b, float c){
#if __has_builtin(__builtin_amdgcn_fdot2)
  return __builtin_amdgcn_fdot2(__builtin_bit_cast(half2_t, a),
                                __builtin_bit_cast(half2_t, b), c, false);
#else
  half2_t ha = __builtin_bit_cast(half2_t, a);
  half2_t hb = __builtin_bit_cast(half2_t, b);
  return c + (float)ha.x*(float)hb.x + (float)ha.y*(float)hb.y;
#endif
}

__device__ __forceinline__ uint32_t packf16(float x, float y){
  union { f16 h[2]; uint32_t u; } z;
  z.h[0] = (f16)x; z.h[1] = (f16)y;
  return z.u;
}

template<int CTRL>
__device__ __forceinline__ float dpp_xor_add(float x){
  int v = __builtin_amdgcn_update_dpp(0, __float_as_int(x), CTRL, 0xF, 0xF, true);
  return x + __int_as_float(v);
}

// full 8-lane (ks) reduce of 4 accs; returns total for row jg + 64*(ks&3)
__device__ __forceinline__ float reduce8(float a0, float a1, float a2, float a3, int k3){
  a0 = dpp_xor_add<0xB1>(a0); a1 = dpp_xor_add<0xB1>(a1);
  a2 = dpp_xor_add<0xB1>(a2); a3 = dpp_xor_add<0xB1>(a3);
  a0 = dpp_xor_add<0x4E>(a0); a1 = dpp_xor_add<0x4E>(a1);
  a2 = dpp_xor_add<0x4E>(a2); a3 = dpp_xor_add<0x4E>(a3);
  float own = (k3==0)?a0:(k3==1)?a1:(k3==2)?a2:a3;
  return own + __shfl_xor(own, 4);
}

// ---------------------------------------------------------------------------
// P0: W_hh fp32 -> f16 into d_ws
// ---------------------------------------------------------------------------
__global__ __launch_bounds__(256) void cvt_w_kernel(const float* __restrict__ wf,
                                                    const float* __restrict__ wb,
                                                    f16* __restrict__ out){
  int i = blockIdx.x*256 + threadIdx.x;
  const float* src = (i < 32768) ? wf : wb;
  int base = (i & 32767) * 8;
  float4 a = *(const float4*)(src + base);
  float4 c = *(const float4*)(src + base + 4);
  uint4 o;
  o.x = packf16(a.x, a.y); o.y = packf16(a.z, a.w);
  o.z = packf16(c.x, c.y); o.w = packf16(c.z, c.w);
  *(uint4*)(out + (size_t)i*8) = o;
}

// ---------------------------------------------------------------------------
// P1: xp staged into d_out (read once by rnn, then overwritten with h).
// ---------------------------------------------------------------------------
#define PTM 128
#define PTN 64
#define PTK 32
__global__ __launch_bounds__(256) void proj_kernel(
    const float* __restrict__ x,
    const float* __restrict__ wihf, const float* __restrict__ wihb,
    const float* __restrict__ bihf, const float* __restrict__ bhhf,
    const float* __restrict__ bihb, const float* __restrict__ bhhb,
    float* __restrict__ out)
{
  __shared__ float As[PTK][132];
  __shared__ float Bs[PTK][68];
  const int tid = threadIdx.x;
  const int row0 = blockIdx.x * PTM;
  const int j0   = blockIdx.y * PTN;
  const int dir  = (j0 >= 512) ? 1 : 0;
  const int jl0  = j0 - dir*512;
  const float* wih = dir ? wihb : wihf;
  const float* bi  = dir ? bihb : bihf;
  const float* bh  = dir ? bhhb : bhhf;

  const int ty = tid >> 4, tx = tid & 15;
  float acc[8][4];
#pragma unroll
  for (int i=0;i<8;i++)
#pragma unroll
    for (int j=0;j<4;j++) acc[i][j] = 0.f;

  float bias[4];
#pragma unroll
  for (int jj=0;jj<4;jj++){ int jl = jl0 + tx*4 + jj; bias[jj] = bi[jl] + bh[jl]; }

  for (int k0 = 0; k0 < I_; k0 += PTK){
    {
      int r = tid >> 1, kh = (tid & 1) * 16;
      int rg = row0 + r; int bb = rg & 31, tt = rg >> 5;
      const float* ap = x + ((size_t)bb*S_ + tt)*I_ + k0 + kh;
#pragma unroll
      for (int u=0;u<4;u++){
        float4 v = *(const float4*)(ap + u*4);
        As[kh+u*4+0][r] = v.x; As[kh+u*4+1][r] = v.y;
        As[kh+u*4+2][r] = v.z; As[kh+u*4+3][r] = v.w;
      }
    }
    {
      int jr = tid >> 2, kh = (tid & 3) * 8;
      const float* bp = wih + (size_t)(jl0 + jr)*I_ + k0 + kh;
#pragma unroll
      for (int u=0;u<2;u++){
        float4 v = *(const float4*)(bp + u*4);
        Bs[kh+u*4+0][jr] = v.x; Bs[kh+u*4+1][jr] = v.y;
        Bs[kh+u*4+2][jr] = v.z; Bs[kh+u*4+3][jr] = v.w;
      }
    }
    __syncthreads();
#pragma unroll 8
    for (int kk=0; kk<PTK; ++kk){
      const float4 a0 = *(const float4*)&As[kk][ty*8+0];
      const float4 a1 = *(const float4*)&As[kk][ty*8+4];
      const float4 bq = *(const float4*)&Bs[kk][tx*4];
      const float av[8] = {a0.x,a0.y,a0.z,a0.w,a1.x,a1.y,a1.z,a1.w};
      const float bv[4] = {bq.x,bq.y,bq.z,bq.w};
#pragma unroll
      for (int i=0;i<8;i++)
#pragma unroll
        for (int j=0;j<4;j++) acc[i][j] = fmaf(av[i], bv[j], acc[i][j]);
    }
    __syncthreads();
  }
#pragma unroll
  for (int i=0;i<8;i++){
    int rg = row0 + ty*8 + i; int bb = rg & 31, tt = rg >> 5;
    float* op = out + ((size_t)bb*S_ + tt)*OUTW + j0 + tx*4;
    float4 v = {acc[i][0]+bias[0], acc[i][1]+bias[1], acc[i][2]+bias[2], acc[i][3]+bias[3]};
    *(float4*)op = v;
  }
}

// ---------------------------------------------------------------------------
// R: partial-exchange recurrence, weights in 128 NAMED scalar VGPRs.
// amdgpu_waves_per_eu(2,2) pins the codegen occupancy target to the HW
// reality (one 8-wave WG per CU -> 2 waves/EU), raising the VGPR pressure
// budget to 256 so the weights can actually stay resident.
// 128 WGs; pair = blocks (p, p+64) -> same XCD. WG owns rows [half*256,+256)
// and k-columns [half*256,+256). Per step: phase A = partials for PARTNER's
// rows (publish tagged f16 ASAP), phase B = own rows; owner lane spins on one
// partner dword, relu, store. One barrier/step. 4 ds_read_b128/lane/step.
// ---------------------------------------------------------------------------
#define MAIL_OFF_U32 (1u<<18)        // W f16 = 1 MB = 2^18 u32
#define MAIL_BYTES   (64*2*2*256*4)  // 256 KB

#define DECL16(P) uint32_t P##_0,P##_1,P##_2,P##_3,P##_4,P##_5,P##_6,P##_7, \
                           P##_8,P##_9,P##_10,P##_11,P##_12,P##_13,P##_14,P##_15
#define LOAD16(P, src) do{ const uint4* _q=(const uint4*)(src); \
  uint4 _v0=_q[0],_v1=_q[1],_v2=_q[2],_v3=_q[3]; \
  P##_0=_v0.x; P##_1=_v0.y; P##_2=_v0.z; P##_3=_v0.w; \
  P##_4=_v1.x; P##_5=_v1.y; P##_6=_v1.z; P##_7=_v1.w; \
  P##_8=_v2.x; P##_9=_v2.y; P##_10=_v2.z; P##_11=_v2.w; \
  P##_12=_v3.x;P##_13=_v3.y;P##_14=_v3.z;P##_15=_v3.w; }while(0)
#define KEEP16(P) asm volatile("" : \
  "+v"(P##_0),"+v"(P##_1),"+v"(P##_2),"+v"(P##_3), \
  "+v"(P##_4),"+v"(P##_5),"+v"(P##_6),"+v"(P##_7), \
  "+v"(P##_8),"+v"(P##_9),"+v"(P##_10),"+v"(P##_11), \
  "+v"(P##_12),"+v"(P##_13),"+v"(P##_14),"+v"(P##_15))
#define DOT16(ACC, P) \
  ACC=fdot2(P##_0 ,hv0.x,ACC); ACC=fdot2(P##_1 ,hv0.y,ACC); \
  ACC=fdot2(P##_2 ,hv0.z,ACC); ACC=fdot2(P##_3 ,hv0.w,ACC); \
  ACC=fdot2(P##_4 ,hv1.x,ACC); ACC=fdot2(P##_5 ,hv1.y,ACC); \
  ACC=fdot2(P##_6 ,hv1.z,ACC); ACC=fdot2(P##_7 ,hv1.w,ACC); \
  ACC=fdot2(P##_8 ,hv2.x,ACC); ACC=fdot2(P##_9 ,hv2.y,ACC); \
  ACC=fdot2(P##_10,hv2.z,ACC); ACC=fdot2(P##_11,hv2.w,ACC); \
  ACC=fdot2(P##_12,hv3.x,ACC); ACC=fdot2(P##_13,hv3.y,ACC); \
  ACC=fdot2(P##_14,hv3.z,ACC); ACC=fdot2(P##_15,hv3.w,ACC);

__global__ __launch_bounds__(512)
__attribute__((amdgpu_waves_per_eu(2, 2)))
void rnn_kernel(
    const f16* __restrict__ Wall,   // [2][512][512] f16
    const float* __restrict__ h0,   // [2][32][512]
    float* dout, uint32_t* mailbase)
{
  __shared__ char lds[1024];        // 2 parity x 256 f16 (own-half h, swizzled)
  const int tid   = threadIdx.x;
  const int half  = blockIdx.x >> 6;
  const int pairid= blockIdx.x & 63;
  const int dir   = pairid >> 5;
  const int b     = pairid & 31;
  const int jg    = tid >> 3;
  const int ks    = tid & 7;
  const int k3    = ks & 3;
  const bool owner= (ks < 4);
  const int jl    = jg + 64*k3;     // row (within 256-block) this lane finalizes

  const f16* Wd = Wall + (size_t)dir * (H_*(size_t)H_);
  float* outs = dout + (size_t)b * (S_*OUTW);
  const int col = dir*512 + half*256 + jl;
  float* hn = dout + (size_t)OUTS_ELEMS + ((size_t)dir*B_ + b) * H_;

  uint32_t* mw = mailbase + ((size_t)pairid*2 + half) * 512;       // we write partner rows
  uint32_t* mr = mailbase + ((size_t)pairid*2 + (half^1)) * 512;   // partner writes ours

  // ---- weights into 128 NAMED scalars (8 groups of 16): A* = partner's rows,
  //      B* = own rows; k-slice = own half, ks*32 + [0,32)
  DECL16(A0); DECL16(A1); DECL16(A2); DECL16(A3);
  DECL16(B0); DECL16(B1); DECL16(B2); DECL16(B3);
  {
    const f16* kbase = Wd + half*256 + ks*32;
    LOAD16(A0, kbase + (size_t)((half^1)*256 + jg +   0)*H_);
    LOAD16(A1, kbase + (size_t)((half^1)*256 + jg +  64)*H_);
    LOAD16(A2, kbase + (size_t)((half^1)*256 + jg + 128)*H_);
    LOAD16(A3, kbase + (size_t)((half^1)*256 + jg + 192)*H_);
    LOAD16(B0, kbase + (size_t)( half*256    + jg +   0)*H_);
    LOAD16(B1, kbase + (size_t)( half*256    + jg +  64)*H_);
    LOAD16(B2, kbase + (size_t)( half*256    + jg + 128)*H_);
    LOAD16(B3, kbase + (size_t)( half*256    + jg + 192)*H_);
  }
  // one-time opacity barrier: values become asm results -> cannot be
  // rematerialized from memory; allocator must keep them VGPR-resident.
  KEEP16(A0); KEEP16(A1); KEEP16(A2); KEEP16(A3);
  KEEP16(B0); KEEP16(B1); KEEP16(B2); KEEP16(B3);

  // h LDS layout: logical 16B chunk c (0..31) at physical chunk (c&3)*8+(c>>2)
  const int hwoff = (((jl>>3)&3)*8 + (jl>>5))*16 + (jl&7)*2;   // owner h write
  if (tid < 256){
    int off = (((tid>>3)&3)*8 + (tid>>5))*16 + (tid&7)*2;
    *(f16*)(lds + off) = (f16)h0[((size_t)dir*B_ + b)*H_ + half*256 + tid];
  }
  __syncthreads();

  for (int s=0; s<S_; ++s){
    const int P = s & 1;
    const int t = dir ? (S_-1-s) : s;
    const char* hb = lds + P*512;
    float* xo = outs + (size_t)t*OUTW;
    float xpv = 0.f;
    if (owner) xpv = xo[col];                       // long-latency, hidden by phases

    const uint4 hv0 = *(const uint4*)(hb +       ks*16);
    const uint4 hv1 = *(const uint4*)(hb + 128 + ks*16);
    const uint4 hv2 = *(const uint4*)(hb + 256 + ks*16);
    const uint4 hv3 = *(const uint4*)(hb + 384 + ks*16);

    // ---- phase A: partials for PARTNER's rows; publish ASAP
    {
      float a0=0.f, a1=0.f, a2=0.f, a3=0.f;
      DOT16(a0, A0) DOT16(a1, A1) DOT16(a2, A2) DOT16(a3, A3)
      float totA = reduce8(a0,a1,a2,a3,k3);
      if (owner){
        uint16_t pb = __builtin_bit_cast(uint16_t, (f16)totA);
        uint32_t val = ((uint32_t)pb << 16) | (uint32_t)(s+1);
        __hip_atomic_store(&mw[P*256 + jl], val, __ATOMIC_RELAXED, __HIP_MEMORY_SCOPE_AGENT);
      }
    }
    // ---- phase B: partials for OWN rows (hides partner flight time)
    float totB;
    {
      float b0=0.f, b1=0.f, b2=0.f, b3=0.f;
      DOT16(b0, B0) DOT16(b1, B1) DOT16(b2, B2) DOT16(b3, B3)
      totB = reduce8(b0,b1,b2,b3,k3);
    }
    // ---- finalize: spin on our single partner dword, relu, store
    if (owner){
      const uint32_t tag = (uint32_t)(s+1);
      uint32_t v;
      do {
        v = __hip_atomic_load(&mr[P*256 + jl], __ATOMIC_RELAXED, __HIP_MEMORY_SCOPE_AGENT);
      } while ((v & 0xffffu) != tag);
      float rem = (float)__builtin_bit_cast(f16, (uint16_t)(v >> 16));
      float h = fmaxf(xpv + totB + rem, 0.f);
      xo[col] = h;                                   // overwrite xp slot
      if (s == S_-1) hn[half*256 + jl] = h;
      *(f16*)(lds + (P^1)*512 + hwoff) = (f16)h;
    }
    asm volatile("s_waitcnt lgkmcnt(0)" ::: "memory");
    __builtin_amdgcn_s_barrier();
  }
}

// ---------------------------------------------------------------------------
extern "C" void kernel_launch(void* const* d_in, const int* in_sizes, int n_in,
                              void* d_out, int out_size, void* d_ws, size_t ws_size,
                              hipStream_t stream){
  const float* x    = (const float*)d_in[0];
  const float* h0   = (const float*)d_in[1];
  const float* wihf = (const float*)d_in[2];
  const float* whhf = (const float*)d_in[3];
  const float* bihf = (const float*)d_in[4];
  const float* bhhf = (const float*)d_in[5];
  const float* wihb = (const float*)d_in[6];
  const float* whhb = (const float*)d_in[7];
  const float* bihb = (const float*)d_in[8];
  const float* bhhb = (const float*)d_in[9];
  float* out = (float*)d_out;
  f16* wf16 = (f16*)d_ws;                            // 1 MB
  uint32_t* mail = (uint32_t*)d_ws + MAIL_OFF_U32;   // 256 KB

  hipMemsetAsync((void*)mail, 0, MAIL_BYTES, stream);  // kill stale tags across replays
  cvt_w_kernel<<<256, 256, 0, stream>>>(whhf, whhb, wf16);
  proj_kernel<<<dim3(128, 16), 256, 0, stream>>>(x, wihf, wihb, bihf, bhhf, bihb, bhhb, out);
  rnn_kernel<<<128, 512, 0, stream>>>(wf16, h0, out, mail);
}